// Round 5
// baseline (280.914 us; speedup 1.0000x reference)
//
#include <hip/hip_runtime.h>
#include <hip/hip_bf16.h>
#include <hip/hip_fp16.h>

// Bahdanau location-sensitive attention, fused f16-MFMA implementation.
// R5: k_main addressing strength-reduced — persistent register offsets for all
//     LDS reads (immediate-folded subtile offsets), persistent global pointers,
//     XOR buffer toggles; all 8 gloads issued in phase 0. Everything else = R4.
// B=32 T=1536 H=1024 CTX=1024 CONV_OUT=32

constexpr int kB = 32, kT = 1536, kH = 1024, kC = 1024, kCO = 32;
constexpr int kM = kB * kT;      // 49152
constexpr int kKp = 1088;        // padded K: 1024 enc | 32 loc | 32 zero
constexpr int kKf = 1056;        // fallback K (1024|32)

typedef _Float16 f16;
typedef _Float16 f16x8 __attribute__((ext_vector_type(8)));
typedef float f32x4 __attribute__((ext_vector_type(4)));

// ---- primary ws layout (bytes) ----
constexpr size_t W2_A     = 0;                                   // kM*kKp f16 = 106.95 MB
constexpr size_t W2_B     = W2_A + (size_t)kM * kKp * 2;         // kC*kKp f16 = 2.23 MB
constexpr size_t W2_ADD   = W2_B + (size_t)kC * kKp * 2;         // kB*kC f32
constexpr size_t W2_SCORE = W2_ADD + (size_t)kB * kC * 4;        // 4*kM f32
constexpr size_t W2_CTXP  = W2_SCORE + (size_t)4 * kM * 4;       // 8*kB*kH f32
constexpr size_t W2_NEED  = W2_CTXP + (size_t)8 * kB * kH * 4;   // ~111.1 MB

// ---- fallback ws layout (bytes) ----
constexpr size_t WF_B     = 0;
constexpr size_t WF_LOC   = WF_B + (size_t)kC * kKf * 2;
constexpr size_t WF_ADD   = WF_LOC + (size_t)kM * kCO * 2;
constexpr size_t WF_SCORE = WF_ADD + (size_t)kB * kC * 4;
constexpr size_t WF_CTXP  = WF_SCORE + (size_t)4 * kM * 4;

__device__ __forceinline__ void gload16(const void* g, void* l) {
    __builtin_amdgcn_global_load_lds(
        (const __attribute__((address_space(1))) void*)g,
        (__attribute__((address_space(3))) void*)l, 16, 0, 0);
}

// ================================================================ primary path
__global__ void k_cvt(const float* __restrict__ enc, f16* __restrict__ Af) {
    int gid = blockIdx.x * 256 + threadIdx.x;       // < kM*kH/8
    int row = gid >> 7, c8 = gid & 127;
    const float* src = enc + (size_t)row * kH + c8 * 8;
    float4 e0 = *(const float4*)src;
    float4 e1 = *(const float4*)(src + 4);
    union { f16 h[8]; int4 q; } u;
    u.h[0] = (f16)e0.x; u.h[1] = (f16)e0.y; u.h[2] = (f16)e0.z; u.h[3] = (f16)e0.w;
    u.h[4] = (f16)e1.x; u.h[5] = (f16)e1.y; u.h[6] = (f16)e1.z; u.h[7] = (f16)e1.w;
    *(int4*)(Af + (size_t)row * kKp + c8 * 8) = u.q;
}

__global__ void k_loc(const float* __restrict__ la, const float* __restrict__ cw,
                      const float* __restrict__ cb, f16* __restrict__ Af) {
    int m = blockIdx.x * 256 + threadIdx.x;          // < kM
    int b = m / kT, t = m - b * kT;
    float x0 = (t > 0)      ? la[(size_t)b * kT + t - 1] : 0.f;
    float x1 = la[(size_t)b * kT + t];
    float x2 = (t < kT - 1) ? la[(size_t)b * kT + t + 1] : 0.f;
    union { f16 h[32]; int4 q[4]; } u;
#pragma unroll
    for (int k = 0; k < 32; ++k)
        u.h[k] = (f16)(cw[k * 3] * x0 + cw[k * 3 + 1] * x1 + cw[k * 3 + 2] * x2 + cb[k]);
    int4* dst = (int4*)(Af + (size_t)m * kKp + kH);
    dst[0] = u.q[0]; dst[1] = u.q[1]; dst[2] = u.q[2]; dst[3] = u.q[3];
    int4 z = {0, 0, 0, 0};
    dst[4] = z; dst[5] = z; dst[6] = z; dst[7] = z;   // pad cols 1056..1087
}

__global__ void k_prep_b2(const float* __restrict__ V, const float* __restrict__ U,
                          f16* __restrict__ Bf) {
    int c = blockIdx.x;
    for (int k = threadIdx.x; k < kKp; k += 256) {
        float v = (k < kH) ? V[(size_t)c * kH + k]
                : (k < kH + kCO) ? U[(size_t)c * kCO + (k - kH)] : 0.f;
        Bf[(size_t)c * kKp + k] = (f16)v;
    }
}

__global__ void k_prep_add(const float* __restrict__ dec, const float* __restrict__ W,
                           const float* __restrict__ bias, float* __restrict__ add) {
    __shared__ float dl[kH];
    int bb = blockIdx.x >> 2;
    int cc = (blockIdx.x & 3) * 256 + threadIdx.x;
    *(float4*)&dl[threadIdx.x * 4] = *(const float4*)&dec[(size_t)bb * kH + threadIdx.x * 4];
    __syncthreads();
    float acc = bias[cc];
    const float* wr = W + (size_t)cc * kH;
    for (int h = 0; h < kH; h += 4) {
        float4 wv = *(const float4*)&wr[h];
        acc += wv.x * dl[h] + wv.y * dl[h + 1] + wv.z * dl[h + 2] + wv.w * dl[h + 3];
    }
    add[(size_t)bb * kC + cc] = acc;
}

// phase helpers --------------------------------------------------
#define RD_A(x, MI) {                                                                         \
    af[x][0] = *(const f16x8*)(smem + aRd0 + (MI) * 2048);                                    \
    af[x][1] = *(const f16x8*)(smem + aRd1 + (MI) * 2048); }

#define MFMA_Q(Q)                                                                             \
    __builtin_amdgcn_s_setprio(1);                                                            \
    { _Pragma("unroll") for (int ni = 0; ni < 4; ++ni) {                                      \
        acc[2*(Q)][ni]   = __builtin_amdgcn_mfma_f32_16x16x32_f16(af[0][0], bfv[ni][0], acc[2*(Q)][ni],   0, 0, 0); \
        acc[2*(Q)][ni]   = __builtin_amdgcn_mfma_f32_16x16x32_f16(af[0][1], bfv[ni][1], acc[2*(Q)][ni],   0, 0, 0); \
        acc[2*(Q)+1][ni] = __builtin_amdgcn_mfma_f32_16x16x32_f16(af[1][0], bfv[ni][0], acc[2*(Q)+1][ni], 0, 0, 0); \
        acc[2*(Q)+1][ni] = __builtin_amdgcn_mfma_f32_16x16x32_f16(af[1][1], bfv[ni][1], acc[2*(Q)+1][ni], 0, 0, 0); } } \
    __builtin_amdgcn_s_setprio(0);

#define PBAR()                                                                                \
    __builtin_amdgcn_s_barrier();                                                             \
    asm volatile("s_waitcnt lgkmcnt(0)" ::: "memory");                                        \
    __builtin_amdgcn_sched_barrier(0);

// ---------------------------------------------------------------- fused main GEMM
// 256x256 tile, BK=64, 512 thr = 8 waves (2M x 4N), per-wave 128x64.
// LDS: buf[c]: A @ c*65536, B @ c*65536+32768; add_l @131072, w_l @132096.
// All loop addressing via persistent registers: XOR-toggled LDS offsets,
// pointer-bumped global sources, immediate-folded subtile offsets.
__launch_bounds__(512, 2)
__global__ void k_main(const f16* __restrict__ Ag, const f16* __restrict__ Bg,
                       const float* __restrict__ add, const float* __restrict__ wvec,
                       float* __restrict__ spart) {
    __shared__ __align__(16) char smem[133120];
    float* add_l = (float*)(smem + 131072);
    float* w_l   = (float*)(smem + 132096);

    const int tid = threadIdx.x, lane = tid & 63, wave = tid >> 6;
    const int wm = wave >> 2, wn = wave & 3;
    const int raw = blockIdx.x;                       // 768 = 8 XCDs x 96
    const int swz = (raw & 7) * 96 + (raw >> 3);
    const int mt = swz >> 2, nt = swz & 3;            // nt fastest: A strip reuse in-XCD
    const int m0 = mt * 256, n0 = nt * 256;
    const int bb = m0 / kT;

    if (tid < 256) {
        add_l[tid] = add[(size_t)bb * kC + n0 + tid];
        w_l[tid]   = wvec[n0 + tid];
    }

    f32x4 acc[8][4];
#pragma unroll
    for (int i = 0; i < 8; ++i)
#pragma unroll
        for (int j = 0; j < 4; ++j) acc[i][j] = (f32x4){0.f, 0.f, 0.f, 0.f};

    // gload lane mapping: instr j covers rows (wave*32 + j*8 .. +8); lane>>3 = row,
    // lane&7 = LDS 16B slot; global col chunk = slot ^ (row&7).
    const int srow8 = lane >> 3;
    const int sslot = (lane & 7) ^ srow8;
    const f16* aS0 = Ag + (size_t)(m0 + wave * 32 +  0 + srow8) * kKp + sslot * 8;
    const f16* aS1 = Ag + (size_t)(m0 + wave * 32 +  8 + srow8) * kKp + sslot * 8;
    const f16* aS2 = Ag + (size_t)(m0 + wave * 32 + 16 + srow8) * kKp + sslot * 8;
    const f16* aS3 = Ag + (size_t)(m0 + wave * 32 + 24 + srow8) * kKp + sslot * 8;
    const f16* bS0 = Bg + (size_t)(n0 + wave * 32 +  0 + srow8) * kKp + sslot * 8;
    const f16* bS1 = Bg + (size_t)(n0 + wave * 32 +  8 + srow8) * kKp + sslot * 8;
    const f16* bS2 = Bg + (size_t)(n0 + wave * 32 + 16 + srow8) * kKp + sslot * 8;
    const f16* bS3 = Bg + (size_t)(n0 + wave * 32 + 24 + srow8) * kKp + sslot * 8;

    // ---- prologue: stage K-tile 0 into buf 0 (dest = wave slab, linear)
    {
        unsigned d = wave * 4096;
        gload16(aS0, smem + d);          gload16(aS1, smem + d + 1024);
        gload16(aS2, smem + d + 2048);   gload16(aS3, smem + d + 3072);
        gload16(bS0, smem + 32768 + d);        gload16(bS1, smem + 32768 + d + 1024);
        gload16(bS2, smem + 32768 + d + 2048); gload16(bS3, smem + 32768 + d + 3072);
    }
    aS0 += 64; aS1 += 64; aS2 += 64; aS3 += 64;
    bS0 += 64; bS1 += 64; bS2 += 64; bS3 += 64;
    asm volatile("s_waitcnt vmcnt(0) lgkmcnt(0)" ::: "memory");
    __builtin_amdgcn_s_barrier();

    const int g = lane >> 4, rl = lane & 15;

    // persistent LDS offsets (XOR-toggled by 65536 each K-step)
    unsigned sA  = 65536 + wave * 4096;                 // stage dest: A, buf1 first
    unsigned sB  = 65536 + 32768 + wave * 4096;         // stage dest: B
    unsigned aRd0 = (unsigned)((wm * 128 + rl) * 128 + ((0 + g) ^ (rl & 7)) * 16);
    unsigned aRd1 = (unsigned)((wm * 128 + rl) * 128 + ((4 + g) ^ (rl & 7)) * 16);
    unsigned bRd0 = (unsigned)(32768 + (wn * 64 + rl) * 128 + ((0 + g) ^ (rl & 7)) * 16);
    unsigned bRd1 = (unsigned)(32768 + (wn * 64 + rl) * 128 + ((4 + g) ^ (rl & 7)) * 16);

    for (int t = 0; t < 17; ++t) {
        f16x8 bfv[4][2], af[2][2];

        // ===== phase 0: stage ALL of K-tile t+1 (8 gloads); read bfv x8 + af q0
        if (t < 16) {
            gload16(aS0, smem + sA);          gload16(aS1, smem + sA + 1024);
            gload16(aS2, smem + sA + 2048);   gload16(aS3, smem + sA + 3072);
            gload16(bS0, smem + sB);          gload16(bS1, smem + sB + 1024);
            gload16(bS2, smem + sB + 2048);   gload16(bS3, smem + sB + 3072);
        }
#pragma unroll
        for (int ni = 0; ni < 4; ++ni) {
            bfv[ni][0] = *(const f16x8*)(smem + bRd0 + ni * 2048);
            bfv[ni][1] = *(const f16x8*)(smem + bRd1 + ni * 2048);
        }
        RD_A(0, 0) RD_A(1, 1)
        PBAR()
        MFMA_Q(0)
        __builtin_amdgcn_s_barrier();

        // ===== phase 1: read af q1
        RD_A(0, 2) RD_A(1, 3)
        PBAR()
        MFMA_Q(1)
        __builtin_amdgcn_s_barrier();

        // ===== phase 2: read af q2
        RD_A(0, 4) RD_A(1, 5)
        PBAR()
        MFMA_Q(2)
        __builtin_amdgcn_s_barrier();

        // ===== phase 3: read af q3; MFMA; drain next-tile loads (3 phases slack)
        RD_A(0, 6) RD_A(1, 7)
        PBAR()
        MFMA_Q(3)
        asm volatile("s_waitcnt vmcnt(0)" ::: "memory");
        __builtin_amdgcn_s_barrier();

        // toggle buffers, bump global sources
        sA ^= 65536; sB ^= 65536;
        aRd0 ^= 65536; aRd1 ^= 65536; bRd0 ^= 65536; bRd1 ^= 65536;
        aS0 += 64; aS1 += 64; aS2 += 64; aS3 += 64;
        bS0 += 64; bS1 += 64; bS2 += 64; bS3 += 64;
    }

    // ---- epilogue: e = tanh(acc + add[c]); partial score = sum_c e*w[c]
    float (*sred)[128][4] = (float (*)[128][4])(smem + 65536);   // buf1 A region (dead)
    {
        const int gq = lane >> 4;
#pragma unroll
        for (int mi = 0; mi < 8; ++mi) {
#pragma unroll
            for (int i = 0; i < 4; ++i) {
                float p = 0.f;
#pragma unroll
                for (int ni = 0; ni < 4; ++ni) {
                    int cl = wn * 64 + ni * 16 + rl;
                    float e = tanhf(acc[mi][ni][i] + add_l[cl]);
                    p += e * w_l[cl];
                }
                p += __shfl_xor(p, 1);
                p += __shfl_xor(p, 2);
                p += __shfl_xor(p, 4);
                p += __shfl_xor(p, 8);
                if (rl == 0) sred[wm][mi * 16 + gq * 4 + i][wn] = p;
            }
        }
    }
    __syncthreads();
    if (tid < 256) {
        float s = sred[tid >> 7][tid & 127][0] + sred[tid >> 7][tid & 127][1]
                + sred[tid >> 7][tid & 127][2] + sred[tid >> 7][tid & 127][3];
        spart[(size_t)nt * kM + m0 + tid] = s;
    }
}

// ================================================================ fallback path (R1, proven)
__global__ void k_prep_b_fb(const float* __restrict__ V, const float* __restrict__ U,
                            f16* __restrict__ Bf) {
    int idx = blockIdx.x * 256 + threadIdx.x;
    int c = idx / kKf, k = idx - c * kKf;
    float v = (k < kH) ? V[(size_t)c * kH + k] : U[(size_t)c * kCO + (k - kH)];
    Bf[idx] = (f16)v;
}

__global__ void k_loc_fb(const float* __restrict__ la, const float* __restrict__ cw,
                         const float* __restrict__ cb, f16* __restrict__ loc) {
    int m = blockIdx.x * 256 + threadIdx.x;
    int b = m / kT, t = m - b * kT;
    float x0 = (t > 0)      ? la[(size_t)b * kT + t - 1] : 0.f;
    float x1 = la[(size_t)b * kT + t];
    float x2 = (t < kT - 1) ? la[(size_t)b * kT + t + 1] : 0.f;
    union { f16 h[32]; int4 q[4]; } u;
#pragma unroll
    for (int k = 0; k < 32; ++k)
        u.h[k] = (f16)(cw[k * 3] * x0 + cw[k * 3 + 1] * x1 + cw[k * 3 + 2] * x2 + cb[k]);
    int4* dst = (int4*)(loc + (size_t)m * 32);
    dst[0] = u.q[0]; dst[1] = u.q[1]; dst[2] = u.q[2]; dst[3] = u.q[3];
}

__launch_bounds__(512)
__global__ void k_main_fb(const float* __restrict__ enc, const f16* __restrict__ Bf,
                          const f16* __restrict__ loc, const float* __restrict__ add,
                          const float* __restrict__ wvec, float* __restrict__ spart) {
    __shared__ __align__(16) f16 As[128 * 64];
    __shared__ __align__(16) f16 Bs[256 * 64];
    __shared__ float add_l[256], w_l[256];
    __shared__ float sred[2][64][4];

    const int tid = threadIdx.x, lane = tid & 63, wave = tid >> 6;
    const int wm = wave >> 2, wn = wave & 3;
    const int mt = blockIdx.x >> 2, nt = blockIdx.x & 3;
    const int m0 = mt * 128, n0 = nt * 256;
    const int bb = m0 / kT;

    if (tid < 256) {
        add_l[tid] = add[(size_t)bb * kC + n0 + tid];
        w_l[tid]   = wvec[n0 + tid];
    }

    f32x4 acc[4][4];
#pragma unroll
    for (int i = 0; i < 4; ++i)
#pragma unroll
        for (int j = 0; j < 4; ++j) acc[i][j] = (f32x4){0.f, 0.f, 0.f, 0.f};

    const int ar = tid >> 2, aq = tid & 3;
    const int br = tid >> 1, bh = tid & 1;
    const float* ap = enc + (size_t)(m0 + ar) * kH + aq * 16;
    const f16*   bp = Bf + (size_t)(n0 + br) * kKf;
    char* aw = (char*)As + ar * 128;
    char* bw = (char*)Bs + br * 128;
    const int axm = ar & 7, bxm = br & 7;

    for (int step = 0; step < 17; ++step) {
        if (step < 16) {
            const int k0 = step * 64;
            float4 f0 = *(const float4*)(ap + k0);
            float4 f1 = *(const float4*)(ap + k0 + 4);
            float4 f2 = *(const float4*)(ap + k0 + 8);
            float4 f3 = *(const float4*)(ap + k0 + 12);
            union { f16 h[16]; int4 q[2]; } pk;
            pk.h[0] = (f16)f0.x;  pk.h[1] = (f16)f0.y;  pk.h[2] = (f16)f0.z;  pk.h[3] = (f16)f0.w;
            pk.h[4] = (f16)f1.x;  pk.h[5] = (f16)f1.y;  pk.h[6] = (f16)f1.z;  pk.h[7] = (f16)f1.w;
            pk.h[8] = (f16)f2.x;  pk.h[9] = (f16)f2.y;  pk.h[10] = (f16)f2.z; pk.h[11] = (f16)f2.w;
            pk.h[12] = (f16)f3.x; pk.h[13] = (f16)f3.y; pk.h[14] = (f16)f3.z; pk.h[15] = (f16)f3.w;
            *(int4*)(aw + (((aq * 2 + 0) ^ axm) * 16)) = pk.q[0];
            *(int4*)(aw + (((aq * 2 + 1) ^ axm) * 16)) = pk.q[1];
            const char* bs = (const char*)(bp + k0 + bh * 32);
#pragma unroll
            for (int j = 0; j < 4; ++j) {
                int4 v = *(const int4*)(bs + j * 16);
                *(int4*)(bw + (((bh * 4 + j) ^ bxm) * 16)) = v;
            }
        } else {
            int4 v = *(const int4*)(loc + (size_t)(m0 + ar) * 32 + aq * 8);
            *(int4*)(aw + ((aq ^ axm) * 16)) = v;
#pragma unroll
            for (int j = 0; j < 2; ++j) {
                int4 w0 = *(const int4*)(bp + kH + (bh * 2 + j) * 8);
                *(int4*)(bw + (((bh * 2 + j) ^ bxm) * 16)) = w0;
            }
        }
        __syncthreads();
        const int nkk = (step < 16) ? 2 : 1;
        for (int kk = 0; kk < nkk; ++kk) {
            f16x8 af[4], bfr[4];
            const int g = lane >> 4, rl = lane & 15;
#pragma unroll
            for (int mi = 0; mi < 4; ++mi) {
                int row = wm * 64 + mi * 16 + rl;
                af[mi] = *(const f16x8*)((const char*)As + row * 128 + (((kk * 4 + g) ^ (row & 7)) * 16));
            }
#pragma unroll
            for (int ni = 0; ni < 4; ++ni) {
                int row = wn * 64 + ni * 16 + rl;
                bfr[ni] = *(const f16x8*)((const char*)Bs + row * 128 + (((kk * 4 + g) ^ (row & 7)) * 16));
            }
#pragma unroll
            for (int mi = 0; mi < 4; ++mi)
#pragma unroll
                for (int ni = 0; ni < 4; ++ni)
                    acc[mi][ni] = __builtin_amdgcn_mfma_f32_16x16x32_f16(af[mi], bfr[ni], acc[mi][ni], 0, 0, 0);
        }
        __syncthreads();
    }

#pragma unroll
    for (int mi = 0; mi < 4; ++mi) {
#pragma unroll
        for (int i = 0; i < 4; ++i) {
            float p = 0.f;
#pragma unroll
            for (int ni = 0; ni < 4; ++ni) {
                int cl = wn * 64 + ni * 16 + (lane & 15);
                float e = tanhf(acc[mi][ni][i] + add_l[cl]);
                p += e * w_l[cl];
            }
            p += __shfl_xor(p, 1);
            p += __shfl_xor(p, 2);
            p += __shfl_xor(p, 4);
            p += __shfl_xor(p, 8);
            if ((lane & 15) == 0)
                sred[wm][mi * 16 + (lane >> 4) * 4 + i][wn] = p;
        }
    }
    __syncthreads();
    if (tid < 128) {
        int r = tid & 63, w2 = tid >> 6;
        float s = sred[w2][r][0] + sred[w2][r][1] + sred[w2][r][2] + sred[w2][r][3];
        spart[(size_t)nt * kM + m0 + tid] = s;
    }
}

// ================================================================ shared epilogue kernels
__global__ void k_softmax(const float* __restrict__ spart, float* __restrict__ out_align) {
    __shared__ float red[256];
    int b = blockIdx.x, tid = threadIdx.x;
    float v[6];
    float mx = -1e30f;
#pragma unroll
    for (int i = 0; i < 6; ++i) {
        size_t idx = (size_t)b * kT + tid + i * 256;
        float s = spart[idx] + spart[kM + idx] + spart[2 * (size_t)kM + idx] + spart[3 * (size_t)kM + idx];
        v[i] = s; mx = fmaxf(mx, s);
    }
    red[tid] = mx; __syncthreads();
    for (int o = 128; o > 0; o >>= 1) { if (tid < o) red[tid] = fmaxf(red[tid], red[tid + o]); __syncthreads(); }
    mx = red[0]; __syncthreads();
    float sum = 0.f;
#pragma unroll
    for (int i = 0; i < 6; ++i) { v[i] = expf(v[i] - mx); sum += v[i]; }
    red[tid] = sum; __syncthreads();
    for (int o = 128; o > 0; o >>= 1) { if (tid < o) red[tid] += red[tid + o]; __syncthreads(); }
    float inv = 1.f / red[0];
#pragma unroll
    for (int i = 0; i < 6; ++i)
        out_align[(size_t)b * kT + tid + i * 256] = v[i] * inv;
}

__global__ void k_ctx_part(const float* __restrict__ enc, const float* __restrict__ align,
                           float* __restrict__ cpart) {
    __shared__ float al[192];
    int ci = blockIdx.x, b = blockIdx.y, tid = threadIdx.x;
    if (tid < 192) al[tid] = align[(size_t)b * kT + ci * 192 + tid];
    __syncthreads();
    float4 acc = {0.f, 0.f, 0.f, 0.f};
    const float* ep = enc + ((size_t)b * kT + (size_t)ci * 192) * kH + tid * 4;
    for (int t = 0; t < 192; ++t) {
        float a = al[t];
        float4 e = *(const float4*)(ep + (size_t)t * kH);
        acc.x += a * e.x; acc.y += a * e.y; acc.z += a * e.z; acc.w += a * e.w;
    }
    *(float4*)&cpart[((size_t)ci * kB + b) * kH + tid * 4] = acc;
}

__global__ void k_ctx_red(const float* __restrict__ cpart, float* __restrict__ out_ctx) {
    int idx = blockIdx.x * 256 + threadIdx.x;
    float s = 0.f;
#pragma unroll
    for (int ci = 0; ci < 8; ++ci) s += cpart[(size_t)ci * kB * kH + idx];
    out_ctx[idx] = s;
}

// ---------------------------------------------------------------- launch
extern "C" void kernel_launch(void* const* d_in, const int* in_sizes, int n_in,
                              void* d_out, int out_size, void* d_ws, size_t ws_size,
                              hipStream_t stream) {
    const float* dec  = (const float*)d_in[0];
    const float* enc  = (const float*)d_in[1];
    const float* la   = (const float*)d_in[2];
    const float* W    = (const float*)d_in[3];
    const float* V    = (const float*)d_in[4];
    const float* U    = (const float*)d_in[5];
    const float* bias = (const float*)d_in[6];
    const float* wv   = (const float*)d_in[7];
    const float* cw   = (const float*)d_in[8];
    const float* cb   = (const float*)d_in[9];

    char* ws = (char*)d_ws;
    float* out_ctx   = (float*)d_out;            // (B,H)
    float* out_align = (float*)d_out + kB * kH;  // (B,T)

    if (ws_size >= W2_NEED) {
        f16* Af      = (f16*)(ws + W2_A);
        f16* Bf      = (f16*)(ws + W2_B);
        float* add   = (float*)(ws + W2_ADD);
        float* spart = (float*)(ws + W2_SCORE);
        float* cpart = (float*)(ws + W2_CTXP);

        hipLaunchKernelGGL(k_prep_b2, dim3(kC),             dim3(256), 0, stream, V, U, Bf);
        hipLaunchKernelGGL(k_loc,     dim3(kM / 256),       dim3(256), 0, stream, la, cw, cb, Af);
        hipLaunchKernelGGL(k_cvt,     dim3(kM * kH / 8 / 256), dim3(256), 0, stream, enc, Af);
        hipLaunchKernelGGL(k_prep_add, dim3(kB * 4),        dim3(256), 0, stream, dec, W, bias, add);
        hipLaunchKernelGGL(k_main,    dim3((kM / 256) * 4), dim3(512), 0, stream, Af, Bf, add, wv, spart);
        hipLaunchKernelGGL(k_softmax, dim3(kB),             dim3(256), 0, stream, spart, out_align);
        hipLaunchKernelGGL(k_ctx_part, dim3(8, kB),         dim3(256), 0, stream, enc, out_align, cpart);
        hipLaunchKernelGGL(k_ctx_red, dim3(kB * kH / 256),  dim3(256), 0, stream, cpart, out_ctx);
    } else {
        f16* Bf      = (f16*)(ws + WF_B);
        f16* loc     = (f16*)(ws + WF_LOC);
        float* add   = (float*)(ws + WF_ADD);
        float* spart = (float*)(ws + WF_SCORE);
        float* cpart = (float*)(ws + WF_CTXP);

        hipLaunchKernelGGL(k_prep_b_fb, dim3(kC * kKf / 256), dim3(256), 0, stream, V, U, Bf);
        hipLaunchKernelGGL(k_loc_fb,  dim3(kM / 256),       dim3(256), 0, stream, la, cw, cb, loc);
        hipLaunchKernelGGL(k_prep_add, dim3(kB * 4),        dim3(256), 0, stream, dec, W, bias, add);
        hipLaunchKernelGGL(k_main_fb, dim3((kM / 128) * 4), dim3(512), 0, stream, enc, Bf, loc, add, wv, spart);
        hipLaunchKernelGGL(k_softmax, dim3(kB),             dim3(256), 0, stream, spart, out_align);
        hipLaunchKernelGGL(k_ctx_part, dim3(8, kB),         dim3(256), 0, stream, enc, out_align, cpart);
        hipLaunchKernelGGL(k_ctx_red, dim3(kB * kH / 256),  dim3(256), 0, stream, cpart, out_ctx);
    }
}

// Round 6
// 272.117 us; speedup vs baseline: 1.0323x; 1.0323x over previous
//
#include <hip/hip_runtime.h>
#include <hip/hip_bf16.h>
#include <hip/hip_fp16.h>

// Bahdanau location-sensitive attention, fused f16-MFMA implementation.
// R6: k_main = half-K-tile slot pipeline with COUNTED vmcnt (never 0 in loop).
//     8 LDS slots (A/B x dbuf x K-half). 4 phases/K-tile split by (K-half, ni-pair).
//     One half-unit staged per phase (2 gload_lds/thread), vmcnt(8) drains 2x/tile,
//     8 loads always in flight. Source-pre-swizzled chunks -> conflict-free ds_read.
// B=32 T=1536 H=1024 CTX=1024 CONV_OUT=32

constexpr int kB = 32, kT = 1536, kH = 1024, kC = 1024, kCO = 32;
constexpr int kM = kB * kT;      // 49152
constexpr int kKp = 1088;        // padded K: 1024 enc | 32 loc | 32 zero
constexpr int kKf = 1056;        // fallback K (1024|32)

typedef _Float16 f16;
typedef _Float16 f16x8 __attribute__((ext_vector_type(8)));
typedef float f32x4 __attribute__((ext_vector_type(4)));

// ---- primary ws layout (bytes) ----
constexpr size_t W2_A     = 0;                                   // kM*kKp f16 = 106.95 MB
constexpr size_t W2_B     = W2_A + (size_t)kM * kKp * 2;         // kC*kKp f16 = 2.23 MB
constexpr size_t W2_ADD   = W2_B + (size_t)kC * kKp * 2;         // kB*kC f32
constexpr size_t W2_SCORE = W2_ADD + (size_t)kB * kC * 4;        // 4*kM f32
constexpr size_t W2_CTXP  = W2_SCORE + (size_t)4 * kM * 4;       // 8*kB*kH f32
constexpr size_t W2_NEED  = W2_CTXP + (size_t)8 * kB * kH * 4;   // ~111.1 MB

// ---- fallback ws layout (bytes) ----
constexpr size_t WF_B     = 0;
constexpr size_t WF_LOC   = WF_B + (size_t)kC * kKf * 2;
constexpr size_t WF_ADD   = WF_LOC + (size_t)kM * kCO * 2;
constexpr size_t WF_SCORE = WF_ADD + (size_t)kB * kC * 4;
constexpr size_t WF_CTXP  = WF_SCORE + (size_t)4 * kM * 4;

__device__ __forceinline__ void gload16(const void* g, void* l) {
    __builtin_amdgcn_global_load_lds(
        (const __attribute__((address_space(1))) void*)g,
        (__attribute__((address_space(3))) void*)l, 16, 0, 0);
}

// ================================================================ primary path
__global__ void k_cvt(const float* __restrict__ enc, f16* __restrict__ Af) {
    int gid = blockIdx.x * 256 + threadIdx.x;       // < kM*kH/8
    int row = gid >> 7, c8 = gid & 127;
    const float* src = enc + (size_t)row * kH + c8 * 8;
    float4 e0 = *(const float4*)src;
    float4 e1 = *(const float4*)(src + 4);
    union { f16 h[8]; int4 q; } u;
    u.h[0] = (f16)e0.x; u.h[1] = (f16)e0.y; u.h[2] = (f16)e0.z; u.h[3] = (f16)e0.w;
    u.h[4] = (f16)e1.x; u.h[5] = (f16)e1.y; u.h[6] = (f16)e1.z; u.h[7] = (f16)e1.w;
    *(int4*)(Af + (size_t)row * kKp + c8 * 8) = u.q;
}

__global__ void k_loc(const float* __restrict__ la, const float* __restrict__ cw,
                      const float* __restrict__ cb, f16* __restrict__ Af) {
    int m = blockIdx.x * 256 + threadIdx.x;          // < kM
    int b = m / kT, t = m - b * kT;
    float x0 = (t > 0)      ? la[(size_t)b * kT + t - 1] : 0.f;
    float x1 = la[(size_t)b * kT + t];
    float x2 = (t < kT - 1) ? la[(size_t)b * kT + t + 1] : 0.f;
    union { f16 h[32]; int4 q[4]; } u;
#pragma unroll
    for (int k = 0; k < 32; ++k)
        u.h[k] = (f16)(cw[k * 3] * x0 + cw[k * 3 + 1] * x1 + cw[k * 3 + 2] * x2 + cb[k]);
    int4* dst = (int4*)(Af + (size_t)m * kKp + kH);
    dst[0] = u.q[0]; dst[1] = u.q[1]; dst[2] = u.q[2]; dst[3] = u.q[3];
    int4 z = {0, 0, 0, 0};
    dst[4] = z; dst[5] = z; dst[6] = z; dst[7] = z;   // pad cols 1056..1087
}

__global__ void k_prep_b2(const float* __restrict__ V, const float* __restrict__ U,
                          f16* __restrict__ Bf) {
    int c = blockIdx.x;
    for (int k = threadIdx.x; k < kKp; k += 256) {
        float v = (k < kH) ? V[(size_t)c * kH + k]
                : (k < kH + kCO) ? U[(size_t)c * kCO + (k - kH)] : 0.f;
        Bf[(size_t)c * kKp + k] = (f16)v;
    }
}

__global__ void k_prep_add(const float* __restrict__ dec, const float* __restrict__ W,
                           const float* __restrict__ bias, float* __restrict__ add) {
    __shared__ float dl[kH];
    int bb = blockIdx.x >> 2;
    int cc = (blockIdx.x & 3) * 256 + threadIdx.x;
    *(float4*)&dl[threadIdx.x * 4] = *(const float4*)&dec[(size_t)bb * kH + threadIdx.x * 4];
    __syncthreads();
    float acc = bias[cc];
    const float* wr = W + (size_t)cc * kH;
    for (int h = 0; h < kH; h += 4) {
        float4 wv = *(const float4*)&wr[h];
        acc += wv.x * dl[h] + wv.y * dl[h + 1] + wv.z * dl[h + 2] + wv.w * dl[h + 3];
    }
    add[(size_t)bb * kC + cc] = acc;
}

// phase helpers --------------------------------------------------
// slot interior: [row 0..255][4 chunks of 16B], phys chunk = global ^ ((row&15)>>1 & 3)
#define RD_AF(SLOT) { _Pragma("unroll") for (int mi = 0; mi < 8; ++mi)                        \
    af[mi] = *(const f16x8*)(smem + (SLOT) * 16384u + aRdBase + mi * 1024u); }

#define RD_BFV(SLOT, NU) {                                                                    \
    bfv[0] = *(const f16x8*)(smem + 65536u + (SLOT) * 16384u + bRdBase + (NU) * 2048u);       \
    bfv[1] = *(const f16x8*)(smem + 65536u + (SLOT) * 16384u + bRdBase + (NU) * 2048u + 1024u); }

#define MFMA_NU(NU)                                                                           \
    __builtin_amdgcn_s_setprio(1);                                                            \
    { _Pragma("unroll") for (int mi = 0; mi < 8; ++mi) {                                      \
        acc[mi][2*(NU)]   = __builtin_amdgcn_mfma_f32_16x16x32_f16(af[mi], bfv[0], acc[mi][2*(NU)],   0, 0, 0); \
        acc[mi][2*(NU)+1] = __builtin_amdgcn_mfma_f32_16x16x32_f16(af[mi], bfv[1], acc[mi][2*(NU)+1], 0, 0, 0); } } \
    __builtin_amdgcn_s_setprio(0);

#define PBAR()                                                                                \
    __builtin_amdgcn_s_barrier();                                                             \
    asm volatile("s_waitcnt lgkmcnt(0)" ::: "memory");                                        \
    __builtin_amdgcn_sched_barrier(0);

#define STAGE_A(KT, KS, SLOT) {                                                               \
    const f16* s_ = aj0 + (KT) * 64 + (KS) * 32;                                              \
    unsigned d_ = (SLOT) * 16384u + dstA;                                                     \
    gload16(s_, smem + d_);                                                                   \
    gload16(s_ + 16 * kKp, smem + d_ + 1024u); }

#define STAGE_B(KT, KS, SLOT) {                                                               \
    const f16* s_ = bj0 + (KT) * 64 + (KS) * 32;                                              \
    unsigned d_ = 65536u + (SLOT) * 16384u + dstA;                                            \
    gload16(s_, smem + d_);                                                                   \
    gload16(s_ + 16 * kKp, smem + d_ + 1024u); }

// ---------------------------------------------------------------- fused main GEMM
// 256x256 tile, BK=64, 512 thr = 8 waves (2M x 4N), per-wave 128x64.
// LDS: A slots (2d+ks)*16384 (64KB), B slots 65536+(2d+ks)*16384 (64KB),
//      add_l @131072, w_l @132096. Slots = 256 rows x 64B, chunk-swizzled.
// Pipeline: phase p stages one half-unit; vmcnt(8) at p1/p3 keeps 8 loads in flight.
__launch_bounds__(512, 2)
__global__ void k_main(const f16* __restrict__ Ag, const f16* __restrict__ Bg,
                       const float* __restrict__ add, const float* __restrict__ wvec,
                       float* __restrict__ spart) {
    __shared__ __align__(16) char smem[133120];
    float* add_l = (float*)(smem + 131072);
    float* w_l   = (float*)(smem + 132096);

    const int tid = threadIdx.x, lane = tid & 63, wave = tid >> 6;
    const int wm = wave >> 2, wn = wave & 3;
    const int raw = blockIdx.x;                       // 768 = 8 XCDs x 96
    const int swz = (raw & 7) * 96 + (raw >> 3);
    const int mt = swz >> 2, nt = swz & 3;            // nt fastest: A strip reuse in-XCD
    const int m0 = mt * 256, n0 = nt * 256;
    const int bb = m0 / kT;

    if (tid < 256) {
        add_l[tid] = add[(size_t)bb * kC + n0 + tid];
        w_l[tid]   = wvec[n0 + tid];
    }

    f32x4 acc[8][4];
#pragma unroll
    for (int i = 0; i < 8; ++i)
#pragma unroll
        for (int j = 0; j < 4; ++j) acc[i][j] = (f32x4){0.f, 0.f, 0.f, 0.f};

    // staging: instr covers 16 consecutive rows x 64B (4 chunk-swizzled 16B lanes/row).
    // lane l -> row (l>>2), phys chunk (l&3) <- global chunk (l&3)^((l>>3)&3).
    const int csw = (((lane & 3) ^ ((lane >> 3) & 3)) * 8);
    const f16* aj0 = Ag + (size_t)(m0 + wave * 32 + (lane >> 2)) * kKp + csw;
    const f16* bj0 = Bg + (size_t)(n0 + wave * 32 + (lane >> 2)) * kKp + csw;
    const unsigned dstA = wave * 2048u;               // 2 rowgroups (1KB each) per wave

    // ds_read bases: row r at byte r*64, phys chunk g^((r&15)>>1 &3)
    const int g = lane >> 4, rl = lane & 15;
    const unsigned aRdBase = (unsigned)((wm * 128 + rl) * 64 + ((g ^ ((rl >> 1) & 3)) << 4));
    const unsigned bRdBase = (unsigned)((wn * 64 + rl) * 64 + ((g ^ ((rl >> 1) & 3)) << 4));

    // ---- prologue: stage ks0(0),ks1(0) -> slots 0,1; ks0(1) -> slot 2; full drain (once)
    STAGE_A(0, 0, 0u) STAGE_B(0, 0, 0u)
    STAGE_A(0, 1, 1u) STAGE_B(0, 1, 1u)
    STAGE_A(1, 0, 2u) STAGE_B(1, 0, 2u)
    asm volatile("s_waitcnt vmcnt(0) lgkmcnt(0)" ::: "memory");
    __builtin_amdgcn_s_barrier();

    for (int t = 0; t < 17; ++t) {
        const int d = t & 1;
        const unsigned sC0 = 2u * d, sC1 = 2u * d + 1u;   // current tile slots (ks0, ks1)
        const unsigned sN1 = 3u - 2u * d;                 // ks1(t+1) slot
        const unsigned sN0 = 2u * d;                      // ks0(t+2) slot (freed after p1)
        const int kt1 = (t + 1 < 16) ? t + 1 : 16;        // clamp: garbage slots never read
        const int kt2 = (t + 2 < 16) ? t + 2 : 16;

        f16x8 af[8], bfv[2];

        // ===== p0 (ks0, ni 0-1): stage A-ks1(t+1)
        STAGE_A(kt1, 1, sN1)
        RD_AF(sC0)
        RD_BFV(sC0, 0)
        PBAR()
        MFMA_NU(0)
        __builtin_amdgcn_s_barrier();

        // ===== p1 (ks0, ni 2-3): stage B-ks1(t+1); mid drain vmcnt(8)
        STAGE_B(kt1, 1, sN1)
        RD_BFV(sC0, 1)
        PBAR()
        MFMA_NU(1)
        asm volatile("s_waitcnt vmcnt(8)" ::: "memory");
        __builtin_amdgcn_s_barrier();

        // ===== p2 (ks1, ni 0-1): stage A-ks0(t+2) into just-freed slot
        STAGE_A(kt2, 0, sN0)
        RD_AF(sC1)
        RD_BFV(sC1, 0)
        PBAR()
        MFMA_NU(0)
        __builtin_amdgcn_s_barrier();

        // ===== p3 (ks1, ni 2-3): stage B-ks0(t+2); end drain vmcnt(8)
        STAGE_B(kt2, 0, sN0)
        RD_BFV(sC1, 1)
        PBAR()
        MFMA_NU(1)
        asm volatile("s_waitcnt vmcnt(8)" ::: "memory");
        __builtin_amdgcn_s_barrier();
    }

    // drain in-flight garbage stages before aliasing LDS
    asm volatile("s_waitcnt vmcnt(0)" ::: "memory");
    __builtin_amdgcn_s_barrier();

    // ---- epilogue: e = tanh(acc + add[c]); partial score = sum_c e*w[c]
    float (*sred)[128][4] = (float (*)[128][4])(smem + 65536);
    {
        const int gq = lane >> 4;
#pragma unroll
        for (int mi = 0; mi < 8; ++mi) {
#pragma unroll
            for (int i = 0; i < 4; ++i) {
                float p = 0.f;
#pragma unroll
                for (int ni = 0; ni < 4; ++ni) {
                    int cl = wn * 64 + ni * 16 + rl;
                    float e = tanhf(acc[mi][ni][i] + add_l[cl]);
                    p += e * w_l[cl];
                }
                p += __shfl_xor(p, 1);
                p += __shfl_xor(p, 2);
                p += __shfl_xor(p, 4);
                p += __shfl_xor(p, 8);
                if (rl == 0) sred[wm][mi * 16 + gq * 4 + i][wn] = p;
            }
        }
    }
    __syncthreads();
    if (tid < 256) {
        float s = sred[tid >> 7][tid & 127][0] + sred[tid >> 7][tid & 127][1]
                + sred[tid >> 7][tid & 127][2] + sred[tid >> 7][tid & 127][3];
        spart[(size_t)nt * kM + m0 + tid] = s;
    }
}

// ================================================================ fallback path (R1, proven)
__global__ void k_prep_b_fb(const float* __restrict__ V, const float* __restrict__ U,
                            f16* __restrict__ Bf) {
    int idx = blockIdx.x * 256 + threadIdx.x;
    int c = idx / kKf, k = idx - c * kKf;
    float v = (k < kH) ? V[(size_t)c * kH + k] : U[(size_t)c * kCO + (k - kH)];
    Bf[idx] = (f16)v;
}

__global__ void k_loc_fb(const float* __restrict__ la, const float* __restrict__ cw,
                         const float* __restrict__ cb, f16* __restrict__ loc) {
    int m = blockIdx.x * 256 + threadIdx.x;
    int b = m / kT, t = m - b * kT;
    float x0 = (t > 0)      ? la[(size_t)b * kT + t - 1] : 0.f;
    float x1 = la[(size_t)b * kT + t];
    float x2 = (t < kT - 1) ? la[(size_t)b * kT + t + 1] : 0.f;
    union { f16 h[32]; int4 q[4]; } u;
#pragma unroll
    for (int k = 0; k < 32; ++k)
        u.h[k] = (f16)(cw[k * 3] * x0 + cw[k * 3 + 1] * x1 + cw[k * 3 + 2] * x2 + cb[k]);
    int4* dst = (int4*)(loc + (size_t)m * 32);
    dst[0] = u.q[0]; dst[1] = u.q[1]; dst[2] = u.q[2]; dst[3] = u.q[3];
}

__launch_bounds__(512)
__global__ void k_main_fb(const float* __restrict__ enc, const f16* __restrict__ Bf,
                          const f16* __restrict__ loc, const float* __restrict__ add,
                          const float* __restrict__ wvec, float* __restrict__ spart) {
    __shared__ __align__(16) f16 As[128 * 64];
    __shared__ __align__(16) f16 Bs[256 * 64];
    __shared__ float add_l[256], w_l[256];
    __shared__ float sred[2][64][4];

    const int tid = threadIdx.x, lane = tid & 63, wave = tid >> 6;
    const int wm = wave >> 2, wn = wave & 3;
    const int mt = blockIdx.x >> 2, nt = blockIdx.x & 3;
    const int m0 = mt * 128, n0 = nt * 256;
    const int bb = m0 / kT;

    if (tid < 256) {
        add_l[tid] = add[(size_t)bb * kC + n0 + tid];
        w_l[tid]   = wvec[n0 + tid];
    }

    f32x4 acc[4][4];
#pragma unroll
    for (int i = 0; i < 4; ++i)
#pragma unroll
        for (int j = 0; j < 4; ++j) acc[i][j] = (f32x4){0.f, 0.f, 0.f, 0.f};

    const int ar = tid >> 2, aq = tid & 3;
    const int br = tid >> 1, bh = tid & 1;
    const float* ap = enc + (size_t)(m0 + ar) * kH + aq * 16;
    const f16*   bp = Bf + (size_t)(n0 + br) * kKf;
    char* aw = (char*)As + ar * 128;
    char* bw = (char*)Bs + br * 128;
    const int axm = ar & 7, bxm = br & 7;

    for (int step = 0; step < 17; ++step) {
        if (step < 16) {
            const int k0 = step * 64;
            float4 f0 = *(const float4*)(ap + k0);
            float4 f1 = *(const float4*)(ap + k0 + 4);
            float4 f2 = *(const float4*)(ap + k0 + 8);
            float4 f3 = *(const float4*)(ap + k0 + 12);
            union { f16 h[16]; int4 q[2]; } pk;
            pk.h[0] = (f16)f0.x;  pk.h[1] = (f16)f0.y;  pk.h[2] = (f16)f0.z;  pk.h[3] = (f16)f0.w;
            pk.h[4] = (f16)f1.x;  pk.h[5] = (f16)f1.y;  pk.h[6] = (f16)f1.z;  pk.h[7] = (f16)f1.w;
            pk.h[8] = (f16)f2.x;  pk.h[9] = (f16)f2.y;  pk.h[10] = (f16)f2.z; pk.h[11] = (f16)f2.w;
            pk.h[12] = (f16)f3.x; pk.h[13] = (f16)f3.y; pk.h[14] = (f16)f3.z; pk.h[15] = (f16)f3.w;
            *(int4*)(aw + (((aq * 2 + 0) ^ axm) * 16)) = pk.q[0];
            *(int4*)(aw + (((aq * 2 + 1) ^ axm) * 16)) = pk.q[1];
            const char* bs = (const char*)(bp + k0 + bh * 32);
#pragma unroll
            for (int j = 0; j < 4; ++j) {
                int4 v = *(const int4*)(bs + j * 16);
                *(int4*)(bw + (((bh * 4 + j) ^ bxm) * 16)) = v;
            }
        } else {
            int4 v = *(const int4*)(loc + (size_t)(m0 + ar) * 32 + aq * 8);
            *(int4*)(aw + ((aq ^ axm) * 16)) = v;
#pragma unroll
            for (int j = 0; j < 2; ++j) {
                int4 w0 = *(const int4*)(bp + kH + (bh * 2 + j) * 8);
                *(int4*)(bw + (((bh * 2 + j) ^ bxm) * 16)) = w0;
            }
        }
        __syncthreads();
        const int nkk = (step < 16) ? 2 : 1;
        for (int kk = 0; kk < nkk; ++kk) {
            f16x8 af[4], bfr[4];
            const int g = lane >> 4, rl = lane & 15;
#pragma unroll
            for (int mi = 0; mi < 4; ++mi) {
                int row = wm * 64 + mi * 16 + rl;
                af[mi] = *(const f16x8*)((const char*)As + row * 128 + (((kk * 4 + g) ^ (row & 7)) * 16));
            }
#pragma unroll
            for (int ni = 0; ni < 4; ++ni) {
                int row = wn * 64 + ni * 16 + rl;
                bfr[ni] = *(const f16x8*)((const char*)Bs + row * 128 + (((kk * 4 + g) ^ (row & 7)) * 16));
            }
#pragma unroll
            for (int mi = 0; mi < 4; ++mi)
#pragma unroll
                for (int ni = 0; ni < 4; ++ni)
                    acc[mi][ni] = __builtin_amdgcn_mfma_f32_16x16x32_f16(af[mi], bfr[ni], acc[mi][ni], 0, 0, 0);
        }
        __syncthreads();
    }

#pragma unroll
    for (int mi = 0; mi < 4; ++mi) {
#pragma unroll
        for (int i = 0; i < 4; ++i) {
            float p = 0.f;
#pragma unroll
            for (int ni = 0; ni < 4; ++ni) {
                int cl = wn * 64 + ni * 16 + (lane & 15);
                float e = tanhf(acc[mi][ni][i] + add_l[cl]);
                p += e * w_l[cl];
            }
            p += __shfl_xor(p, 1);
            p += __shfl_xor(p, 2);
            p += __shfl_xor(p, 4);
            p += __shfl_xor(p, 8);
            if ((lane & 15) == 0)
                sred[wm][mi * 16 + (lane >> 4) * 4 + i][wn] = p;
        }
    }
    __syncthreads();
    if (tid < 128) {
        int r = tid & 63, w2 = tid >> 6;
        float s = sred[w2][r][0] + sred[w2][r][1] + sred[w2][r][2] + sred[w2][r][3];
        spart[(size_t)nt * kM + m0 + tid] = s;
    }
}

// ================================================================ shared epilogue kernels
__global__ void k_softmax(const float* __restrict__ spart, float* __restrict__ out_align) {
    __shared__ float red[256];
    int b = blockIdx.x, tid = threadIdx.x;
    float v[6];
    float mx = -1e30f;
#pragma unroll
    for (int i = 0; i < 6; ++i) {
        size_t idx = (size_t)b * kT + tid + i * 256;
        float s = spart[idx] + spart[kM + idx] + spart[2 * (size_t)kM + idx] + spart[3 * (size_t)kM + idx];
        v[i] = s; mx = fmaxf(mx, s);
    }
    red[tid] = mx; __syncthreads();
    for (int o = 128; o > 0; o >>= 1) { if (tid < o) red[tid] = fmaxf(red[tid], red[tid + o]); __syncthreads(); }
    mx = red[0]; __syncthreads();
    float sum = 0.f;
#pragma unroll
    for (int i = 0; i < 6; ++i) { v[i] = expf(v[i] - mx); sum += v[i]; }
    red[tid] = sum; __syncthreads();
    for (int o = 128; o > 0; o >>= 1) { if (tid < o) red[tid] += red[tid + o]; __syncthreads(); }
    float inv = 1.f / red[0];
#pragma unroll
    for (int i = 0; i < 6; ++i)
        out_align[(size_t)b * kT + tid + i * 256] = v[i] * inv;
}

__global__ void k_ctx_part(const float* __restrict__ enc, const float* __restrict__ align,
                           float* __restrict__ cpart) {
    __shared__ float al[192];
    int ci = blockIdx.x, b = blockIdx.y, tid = threadIdx.x;
    if (tid < 192) al[tid] = align[(size_t)b * kT + ci * 192 + tid];
    __syncthreads();
    float4 acc = {0.f, 0.f, 0.f, 0.f};
    const float* ep = enc + ((size_t)b * kT + (size_t)ci * 192) * kH + tid * 4;
    for (int t = 0; t < 192; ++t) {
        float a = al[t];
        float4 e = *(const float4*)(ep + (size_t)t * kH);
        acc.x += a * e.x; acc.y += a * e.y; acc.z += a * e.z; acc.w += a * e.w;
    }
    *(float4*)&cpart[((size_t)ci * kB + b) * kH + tid * 4] = acc;
}

__global__ void k_ctx_red(const float* __restrict__ cpart, float* __restrict__ out_ctx) {
    int idx = blockIdx.x * 256 + threadIdx.x;
    float s = 0.f;
#pragma unroll
    for (int ci = 0; ci < 8; ++ci) s += cpart[(size_t)ci * kB * kH + idx];
    out_ctx[idx] = s;
}

// ---------------------------------------------------------------- launch
extern "C" void kernel_launch(void* const* d_in, const int* in_sizes, int n_in,
                              void* d_out, int out_size, void* d_ws, size_t ws_size,
                              hipStream_t stream) {
    const float* dec  = (const float*)d_in[0];
    const float* enc  = (const float*)d_in[1];
    const float* la   = (const float*)d_in[2];
    const float* W    = (const float*)d_in[3];
    const float* V    = (const float*)d_in[4];
    const float* U    = (const float*)d_in[5];
    const float* bias = (const float*)d_in[6];
    const float* wv   = (const float*)d_in[7];
    const float* cw   = (const float*)d_in[8];
    const float* cb   = (const float*)d_in[9];

    char* ws = (char*)d_ws;
    float* out_ctx   = (float*)d_out;            // (B,H)
    float* out_align = (float*)d_out + kB * kH;  // (B,T)

    if (ws_size >= W2_NEED) {
        f16* Af      = (f16*)(ws + W2_A);
        f16* Bf      = (f16*)(ws + W2_B);
        float* add   = (float*)(ws + W2_ADD);
        float* spart = (float*)(ws + W2_SCORE);
        float* cpart = (float*)(ws + W2_CTXP);

        hipLaunchKernelGGL(k_prep_b2, dim3(kC),             dim3(256), 0, stream, V, U, Bf);
        hipLaunchKernelGGL(k_loc,     dim3(kM / 256),       dim3(256), 0, stream, la, cw, cb, Af);
        hipLaunchKernelGGL(k_cvt,     dim3(kM * kH / 8 / 256), dim3(256), 0, stream, enc, Af);
        hipLaunchKernelGGL(k_prep_add, dim3(kB * 4),        dim3(256), 0, stream, dec, W, bias, add);
        hipLaunchKernelGGL(k_main,    dim3((kM / 256) * 4), dim3(512), 0, stream, Af, Bf, add, wv, spart);
        hipLaunchKernelGGL(k_softmax, dim3(kB),             dim3(256), 0, stream, spart, out_align);
        hipLaunchKernelGGL(k_ctx_part, dim3(8, kB),         dim3(256), 0, stream, enc, out_align, cpart);
        hipLaunchKernelGGL(k_ctx_red, dim3(kB * kH / 256),  dim3(256), 0, stream, cpart, out_ctx);
    } else {
        f16* Bf      = (f16*)(ws + WF_B);
        f16* loc     = (f16*)(ws + WF_LOC);
        float* add   = (float*)(ws + WF_ADD);
        float* spart = (float*)(ws + WF_SCORE);
        float* cpart = (float*)(ws + WF_CTXP);

        hipLaunchKernelGGL(k_prep_b_fb, dim3(kC * kKf / 256), dim3(256), 0, stream, V, U, Bf);
        hipLaunchKernelGGL(k_loc_fb,  dim3(kM / 256),       dim3(256), 0, stream, la, cw, cb, loc);
        hipLaunchKernelGGL(k_prep_add, dim3(kB * 4),        dim3(256), 0, stream, dec, W, bias, add);
        hipLaunchKernelGGL(k_main_fb, dim3((kM / 128) * 4), dim3(512), 0, stream, enc, Bf, loc, add, wv, spart);
        hipLaunchKernelGGL(k_softmax, dim3(kB),             dim3(256), 0, stream, spart, out_align);
        hipLaunchKernelGGL(k_ctx_part, dim3(8, kB),         dim3(256), 0, stream, enc, out_align, cpart);
        hipLaunchKernelGGL(k_ctx_red, dim3(kB * kH / 256),  dim3(256), 0, stream, cpart, out_ctx);
    }
}